// Round 2
// baseline (578.305 us; speedup 1.0000x reference)
//
#include <hip/hip_runtime.h>

#define NQ 12
#define NLAYERS 6
#define XROW 150528   // 3*224*224

// State-vector simulator, one wave (64 threads) per batch element.
// Global amplitude index g = (lane << 6) | local, local in [0,64).
//   global bit p (p>=6) -> lane bit (p-6);  p<6 -> local bit p.
// Wire j <-> global bit (11-j):
//   wires 0..5  -> lane bits 5..0   (gates via __shfl_xor)
//   wires 6..11 -> local bits 5..0  (gates pure in-register FMA)

__global__ __launch_bounds__(64, 1) void qnn_kernel(
    const float* __restrict__ x,      // (512, 150528), only first 12 per row used
    const float* __restrict__ w,      // (6, 12, 3)
    const float* __restrict__ bias,   // scalar
    float* __restrict__ out)          // (512)
{
    const int b    = blockIdx.x;
    const int lane = threadIdx.x;     // 0..63 (one wave)

    float vr[64], vi[64];

    const float* xb = x + (size_t)b * XROW;

    // ---- AngleEmbedding RX(f_j): product state ----
    // amp(v) = prod_j [ v_j ? -i*sin(f_j/2) : cos(f_j/2) ]
    // lane-part product (wires 0..5, lane bit 5-j):
    float pr = 1.f, pi_ = 0.f;
    #pragma unroll
    for (int j = 0; j < 6; ++j) {
        const float half = xb[j] * 0.5f;
        const float c = __cosf(half), s = __sinf(half);
        const int bit = (lane >> (5 - j)) & 1;
        const float fr = bit ? 0.f : c;
        const float fi = bit ? -s : 0.f;
        const float nr = pr * fr - pi_ * fi;
        const float ni = pr * fi + pi_ * fr;
        pr = nr; pi_ = ni;
    }
    vr[0] = pr; vi[0] = pi_;
    // local-part doubling (bit bb <-> wire 11-bb):
    #pragma unroll
    for (int bb = 0; bb < 6; ++bb) {
        const int wireJ = 11 - bb;
        const float half = xb[wireJ] * 0.5f;
        const float c = __cosf(half), s = __sinf(half);
        const int m = 1 << bb;
        #pragma unroll
        for (int l = 0; l < 64; ++l) {
            if (l < m) {
                const float r = vr[l], q = vi[l];
                vr[l + m] = q * s;      // v * (0,-s)
                vi[l + m] = -r * s;
                vr[l] = r * c;          // v * (c,0)
                vi[l] = q * c;
            }
        }
    }

    // ---- layers ----
    for (int layer = 0; layer < NLAYERS; ++layer) {
        const float* wl = w + layer * NQ * 3;

        // 12 Rot gates (distinct wires -> commute; grouped by type)
        // wires 0..5: lane-bit gates
        #pragma unroll
        for (int j = 0; j < 6; ++j) {
            const float phi = wl[j * 3 + 0], th = wl[j * 3 + 1], om = wl[j * 3 + 2];
            const float ct = __cosf(th * 0.5f), st = __sinf(th * 0.5f);
            const float sp = 0.5f * (phi + om), dm = 0.5f * (phi - om);
            const float csp = __cosf(sp), ssp = __sinf(sp);
            const float cdm = __cosf(dm), sdm = __sinf(dm);
            const float ar =  csp * ct, ai = -ssp * ct;   // a
            const float br = -cdm * st, bi = -sdm * st;   // b
            const float cr =  cdm * st, ci = -sdm * st;   // c
            const float dr =  csp * ct, di =  ssp * ct;   // d
            const int wb = 5 - j;
            const int myb = (lane >> wb) & 1;
            const float cmr = myb ? dr : ar, cmi = myb ? di : ai;
            const float ctr = myb ? cr : br, cti = myb ? ci : bi;
            #pragma unroll
            for (int l = 0; l < 64; ++l) {
                const float tr = __shfl_xor(vr[l], 1 << wb, 64);
                const float ti = __shfl_xor(vi[l], 1 << wb, 64);
                const float mr = vr[l], mi = vi[l];
                vr[l] = cmr * mr - cmi * mi + ctr * tr - cti * ti;
                vi[l] = cmr * mi + cmi * mr + ctr * ti + cti * tr;
            }
        }
        // wires 6..11: local-bit gates
        #pragma unroll
        for (int j = 6; j < 12; ++j) {
            const float phi = wl[j * 3 + 0], th = wl[j * 3 + 1], om = wl[j * 3 + 2];
            const float ct = __cosf(th * 0.5f), st = __sinf(th * 0.5f);
            const float sp = 0.5f * (phi + om), dm = 0.5f * (phi - om);
            const float csp = __cosf(sp), ssp = __sinf(sp);
            const float cdm = __cosf(dm), sdm = __sinf(dm);
            const float ar =  csp * ct, ai = -ssp * ct;
            const float br = -cdm * st, bi = -sdm * st;
            const float cr =  cdm * st, ci = -sdm * st;
            const float dr =  csp * ct, di =  ssp * ct;
            const int step = 1 << (11 - j);
            #pragma unroll
            for (int l0 = 0; l0 < 64; ++l0) {
                if (!(l0 & step)) {
                    const int l1 = l0 | step;
                    const float r0 = vr[l0], i0 = vi[l0];
                    const float r1 = vr[l1], i1 = vi[l1];
                    vr[l0] = ar * r0 - ai * i0 + br * r1 - bi * i1;
                    vi[l0] = ar * i0 + ai * r0 + br * i1 + bi * r1;
                    vr[l1] = cr * r0 - ci * i0 + dr * r1 - di * i1;
                    vi[l1] = cr * i0 + ci * r0 + dr * i1 + di * r1;
                }
            }
        }

        // CNOT ring, in order j=0..11
        // j=0..4: ctrl lane bit (5-j), tgt lane bit (4-j)
        #pragma unroll
        for (int j = 0; j < 5; ++j) {
            const int cb = 5 - j;
            const int tmask = 1 << (4 - j);
            const bool doit = (lane >> cb) & 1;
            #pragma unroll
            for (int l = 0; l < 64; ++l) {
                const float tr = __shfl_xor(vr[l], tmask, 64);
                const float ti = __shfl_xor(vi[l], tmask, 64);
                vr[l] = doit ? tr : vr[l];
                vi[l] = doit ? ti : vi[l];
            }
        }
        // j=5: ctrl lane bit 0, tgt local bit 5
        {
            const bool doit = lane & 1;
            #pragma unroll
            for (int l = 0; l < 32; ++l) {
                const float r0 = vr[l], i0 = vi[l];
                const float r1 = vr[l + 32], i1 = vi[l + 32];
                vr[l]      = doit ? r1 : r0;  vi[l]      = doit ? i1 : i0;
                vr[l + 32] = doit ? r0 : r1;  vi[l + 32] = doit ? i0 : i1;
            }
        }
        // j=6..10: both bits local -> static register permutation (free)
        #pragma unroll
        for (int j = 6; j < 11; ++j) {
            const int cmask = 1 << (11 - j);
            const int tmask = 1 << (10 - j);
            #pragma unroll
            for (int l = 0; l < 64; ++l) {
                if ((l & cmask) && !(l & tmask)) {
                    const int p = l | tmask;
                    const float tr = vr[l]; vr[l] = vr[p]; vr[p] = tr;
                    const float ti = vi[l]; vi[l] = vi[p]; vi[p] = ti;
                }
            }
        }
        // j=11: ctrl local bit 0, tgt lane bit 5
        #pragma unroll
        for (int l = 1; l < 64; l += 2) {
            vr[l] = __shfl_xor(vr[l], 32, 64);
            vi[l] = __shfl_xor(vi[l], 32, 64);
        }
    }

    // ---- <Z_0>: wire 0 = lane bit 5 ----
    float acc = 0.f;
    #pragma unroll
    for (int l = 0; l < 64; ++l) acc += vr[l] * vr[l] + vi[l] * vi[l];
    if (lane & 32) acc = -acc;
    #pragma unroll
    for (int off = 32; off > 0; off >>= 1)
        acc += __shfl_down(acc, off, 64);
    if (lane == 0) out[b] = acc + bias[0];
}

extern "C" void kernel_launch(void* const* d_in, const int* in_sizes, int n_in,
                              void* d_out, int out_size, void* d_ws, size_t ws_size,
                              hipStream_t stream) {
    const float* x    = (const float*)d_in[0];
    const float* wts  = (const float*)d_in[1];
    const float* bias = (const float*)d_in[2];
    float* out = (float*)d_out;
    qnn_kernel<<<out_size, 64, 0, stream>>>(x, wts, bias, out);
}

// Round 3
// 382.488 us; speedup vs baseline: 1.5120x; 1.5120x over previous
//
#include <hip/hip_runtime.h>

#define NLAYERS 6
#define XROW 150528   // 3*224*224

// ---------------------------------------------------------------------------
// 12-qubit state-vector sim, one block (4 waves, 256 threads) per batch elem.
// 16 amplitudes per lane (4 "local" register bits), 6 "lane" bits, 2 "wave"
// bits. Three mapping phases; in each phase 4 wires are local so their Rot
// gates are pure FMA and ring-CNOTs are free register renames. LDS remaps
// rotate the mapping (XOR-swizzled against bank conflicts).
//   Phase A: local L3..L0 = wires 0..3 ; lane N5..N0 = wires 4..9 ; wave = 10,11
//   Phase B: local = wires 4..7 ; lane = wires 0,1,2,3,8,9 ; wave = 10,11
//   Phase C: local = wires 8..11; lane = wires 0..5       ; wave = 6,7
// Boundary CNOTs: (3->4) per-lane select in B; (7->8) wave-uniform select in
// C; (11->0) folded into the C->A remap read (or final measurement sign).
// ---------------------------------------------------------------------------

// prep: per-gate Rot coefficients (a,b,c,d complex) -> d_ws (72*8 floats)
__global__ void qnn_prep(const float* __restrict__ w, float* __restrict__ coef) {
    const int g = threadIdx.x;
    if (g < NLAYERS * 12) {
        const float phi = w[g*3+0], th = w[g*3+1], om = w[g*3+2];
        const float ct = cosf(0.5f*th), st = sinf(0.5f*th);
        const float sp = 0.5f*(phi+om), dm = 0.5f*(phi-om);
        const float csp = cosf(sp), ssp = sinf(sp);
        const float cdm = cosf(dm), sdm = sinf(dm);
        float* c = coef + g*8;
        c[0] =  csp*ct; c[1] = -ssp*ct;   // a = e^{-i(phi+om)/2} ct
        c[2] = -cdm*st; c[3] = -sdm*st;   // b = -e^{+i(phi-om)/2} st
        c[4] =  cdm*st; c[5] = -sdm*st;   // c = e^{-i(phi-om)/2} st
        c[6] =  csp*ct; c[7] =  ssp*ct;   // d = e^{+i(phi+om)/2} ct
    }
}

template<int BP>
__device__ __forceinline__ void rot_local(float (&vr)[16], float (&vi)[16],
                                          const float* __restrict__ cf) {
    const float ar = cf[0], ai = cf[1], br = cf[2], bi = cf[3];
    const float cr = cf[4], ci = cf[5], dr = cf[6], di = cf[7];
    #pragma unroll
    for (int l0 = 0; l0 < 16; ++l0) {
        if (!(l0 & (1 << BP))) {
            const int l1 = l0 | (1 << BP);
            const float r0 = vr[l0], i0 = vi[l0];
            const float r1 = vr[l1], i1 = vi[l1];
            vr[l0] = ar*r0 - ai*i0 + br*r1 - bi*i1;
            vi[l0] = ar*i0 + ai*r0 + br*i1 + bi*r1;
            vr[l1] = cr*r0 - ci*i0 + dr*r1 - di*i1;
            vi[l1] = cr*i0 + ci*r0 + dr*i1 + di*r1;
        }
    }
}

#define SWAP_AMP(A,B) { float t_ = vr[A]; vr[A] = vr[B]; vr[B] = t_; \
                        t_ = vi[A]; vi[A] = vi[B]; vi[B] = t_; }
// free ring-CNOTs inside a phase (ctrl bit3->tgt bit2, bit2->1, bit1->0):
#define RING_CNOTS_LOCAL() \
    SWAP_AMP(8,12) SWAP_AMP(9,13) SWAP_AMP(10,14) SWAP_AMP(11,15) \
    SWAP_AMP(4,6)  SWAP_AMP(5,7)  SWAP_AMP(12,14) SWAP_AMP(13,15) \
    SWAP_AMP(2,3)  SWAP_AMP(6,7)  SWAP_AMP(10,11) SWAP_AMP(14,15)

__global__ __launch_bounds__(256, 2) void qnn_kernel(
    const float* __restrict__ x,      // (512, 150528): only first 12 per row
    const float* __restrict__ coef,   // (72, 8) from qnn_prep
    const float* __restrict__ bias,   // scalar
    float* __restrict__ out)          // (512)
{
    __shared__ float2 st[4096];       // 32 KB remap buffer
    __shared__ float partial[4];

    const int tid  = threadIdx.x;     // 0..255
    const int lane = tid & 63;
    const int wv   = tid >> 6;        // 0..3
    const int b    = blockIdx.x;

    float vr[16], vi[16];

    // ---- AngleEmbedding RX product state, built directly in phase A ----
    const float* xb = x + (size_t)b * XROW;
    float fc[12], fs[12];
    #pragma unroll
    for (int j = 0; j < 12; ++j) {
        const float h = xb[j] * 0.5f;
        fc[j] = __cosf(h);
        fs[j] = __sinf(h);
    }
    // fixed wires: 4..9 on lane bits 5..0, 10,11 on wave bits 1,0
    float pr = 1.f, pi_ = 0.f;
    #pragma unroll
    for (int j = 4; j < 12; ++j) {
        const int bit = (j < 10) ? ((lane >> (9 - j)) & 1)
                                 : ((j == 10) ? ((wv >> 1) & 1) : (wv & 1));
        const float nr = bit ? (pi_ * fs[j]) : (pr * fc[j]);
        const float ni = bit ? (-pr * fs[j]) : (pi_ * fc[j]);
        pr = nr; pi_ = ni;
    }
    // local wires 0..3 on local bits 3..0, doubling
    vr[0] = pr; vi[0] = pi_;
    #pragma unroll
    for (int bb = 0; bb < 4; ++bb) {
        const int wire = 3 - bb;          // bit bb hosts wire 3-bb
        const float cc = fc[wire], ss = fs[wire];
        const int m = 1 << bb;
        #pragma unroll
        for (int l = 0; l < 8; ++l) {
            if (l < m) {
                const float r = vr[l], q = vi[l];
                vr[l + m] = q * ss;
                vi[l + m] = -r * ss;
                vr[l] = r * cc;
                vi[l] = q * cc;
            }
        }
    }

    // ---- layers ----
    for (int layer = 0; layer < NLAYERS; ++layer) {
        const float* cl = coef + layer * 12 * 8;

        if (layer) {
            // remap C -> A, folding previous layer's CNOT(11->0)
            #pragma unroll
            for (int l = 0; l < 16; ++l)
                st[(l << 8) | (tid ^ l ^ wv)] = make_float2(vr[l], vi[l]);
            __syncthreads();
            {
                const int l_old = ((lane & 3) << 2) | wv;
                const int w_old = (lane >> 2) & 3;
                const int n_lo  = (lane >> 4) & 3;
                const int fold  = (wv & 1) << 3;     // flip wire0 where wire11=1
                #pragma unroll
                for (int l = 0; l < 16; ++l) {
                    const int lp2   = l ^ fold;
                    const int n_old = (lp2 << 2) | n_lo;
                    const int t_old = (w_old << 6) | n_old;
                    const float2 v  = st[(l_old << 8) | (t_old ^ l_old ^ w_old)];
                    vr[l] = v.x; vi[l] = v.y;
                }
            }
            __syncthreads();
        }

        // ---- phase A: Rot wires 0..3 (bp 3..0), CNOT(0->1),(1->2),(2->3) ----
        rot_local<3>(vr, vi, cl + 0*8);
        rot_local<2>(vr, vi, cl + 1*8);
        rot_local<1>(vr, vi, cl + 2*8);
        rot_local<0>(vr, vi, cl + 3*8);
        RING_CNOTS_LOCAL();

        // ---- remap A -> B ----
        #pragma unroll
        for (int l = 0; l < 16; ++l)
            st[(l << 8) | (tid ^ (l << 2))] = make_float2(vr[l], vi[l]);
        __syncthreads();
        {
            const int l_old = (lane >> 2) & 0xF;
            const int n_lo  = lane & 3;
            #pragma unroll
            for (int l = 0; l < 16; ++l) {
                const int n_old = (l << 2) | n_lo;
                const int t_old = (wv << 6) | n_old;
                const float2 v  = st[(l_old << 8) | (t_old ^ (l_old << 2))];
                vr[l] = v.x; vi[l] = v.y;
            }
        }
        __syncthreads();

        // ---- phase B: Rot wires 4..7, CNOT(3->4) cond, (4->5),(5->6),(6->7) ----
        rot_local<3>(vr, vi, cl + 4*8);
        rot_local<2>(vr, vi, cl + 5*8);
        rot_local<1>(vr, vi, cl + 6*8);
        rot_local<0>(vr, vi, cl + 7*8);
        {
            const bool sel = (lane >> 2) & 1;   // ctrl wire3 on lane bit N2
            #pragma unroll
            for (int l = 0; l < 8; ++l) {
                const float a0 = vr[l], a1 = vr[l + 8];
                vr[l] = sel ? a1 : a0;  vr[l + 8] = sel ? a0 : a1;
                const float b0 = vi[l], b1 = vi[l + 8];
                vi[l] = sel ? b1 : b0;  vi[l + 8] = sel ? b0 : b1;
            }
        }
        RING_CNOTS_LOCAL();

        // ---- remap B -> C ----
        #pragma unroll
        for (int l = 0; l < 16; ++l) {
            const int sw = ((l & 1) << 3) | ((l & 2) << 1) | ((l & 4) >> 1) | ((l & 8) >> 3);
            st[(l << 8) | (tid ^ sw)] = make_float2(vr[l], vi[l]);
        }
        __syncthreads();
        {
            const int l_old = ((lane & 3) << 2) | wv;
            const int swo = ((l_old & 1) << 3) | ((l_old & 2) << 1)
                          | ((l_old & 4) >> 1) | ((l_old & 8) >> 3);
            const int n_hi = ((lane >> 2) & 0xF) << 2;
            #pragma unroll
            for (int l = 0; l < 16; ++l) {
                const int n_old = n_hi | (l >> 2);
                const int w_old = l & 3;            // wires 10,11 from old wave
                const int t_old = (w_old << 6) | n_old;
                const float2 v  = st[(l_old << 8) | (t_old ^ swo)];
                vr[l] = v.x; vi[l] = v.y;
            }
        }
        __syncthreads();

        // ---- phase C: Rot wires 8..11, CNOT(7->8) cond, (8->9),(9->10),(10->11) ----
        rot_local<3>(vr, vi, cl + 8*8);
        rot_local<2>(vr, vi, cl + 9*8);
        rot_local<1>(vr, vi, cl + 10*8);
        rot_local<0>(vr, vi, cl + 11*8);
        {
            const bool sel = wv & 1;            // ctrl wire7 on wave bit W0
            #pragma unroll
            for (int l = 0; l < 8; ++l) {
                const float a0 = vr[l], a1 = vr[l + 8];
                vr[l] = sel ? a1 : a0;  vr[l + 8] = sel ? a0 : a1;
                const float b0 = vi[l], b1 = vi[l + 8];
                vi[l] = sel ? b1 : b0;  vi[l + 8] = sel ? b0 : b1;
            }
        }
        RING_CNOTS_LOCAL();
        // CNOT(11->0) folded into next remap / final measurement sign
    }

    // ---- <Z_0> with folded CNOT(11->0): sign = wire0 ^ wire11 = lane[5] ^ l[0]
    float acc = 0.f;
    #pragma unroll
    for (int l = 0; l < 16; ++l) {
        const float p = vr[l] * vr[l] + vi[l] * vi[l];
        acc += ((((lane >> 5) ^ l) & 1) ? -p : p);
    }
    #pragma unroll
    for (int off = 32; off > 0; off >>= 1)
        acc += __shfl_down(acc, off, 64);
    if ((lane) == 0) partial[wv] = acc;
    __syncthreads();
    if (tid == 0)
        out[b] = partial[0] + partial[1] + partial[2] + partial[3] + bias[0];
}

extern "C" void kernel_launch(void* const* d_in, const int* in_sizes, int n_in,
                              void* d_out, int out_size, void* d_ws, size_t ws_size,
                              hipStream_t stream) {
    const float* x    = (const float*)d_in[0];
    const float* wts  = (const float*)d_in[1];
    const float* bias = (const float*)d_in[2];
    float* out  = (float*)d_out;
    float* coef = (float*)d_ws;       // 72*8 floats = 2304 B
    qnn_prep<<<1, 128, 0, stream>>>(wts, coef);
    qnn_kernel<<<out_size, 256, 0, stream>>>(x, coef, bias, out);
}

// Round 4
// 371.270 us; speedup vs baseline: 1.5576x; 1.0302x over previous
//
#include <hip/hip_runtime.h>

#define NLAYERS 6
#define XROW 150528   // 3*224*224

typedef float v2f __attribute__((ext_vector_type(2)));

// ---------------------------------------------------------------------------
// 12-qubit state-vector sim, one block (4 waves, 256 threads) per batch elem.
// 16 amplitudes per lane as float2 (re,im) -> v_pk_fma_f32 packed math.
// Three mapping phases (4 wires local each); XOR-swizzled LDS remaps rotate
// the mapping. Double-buffered staging -> ONE barrier per remap (17 total).
//   Phase A: local L3..L0 = wires 0..3 ; lane N5..N0 = wires 4..9 ; wave = 10,11
//   Phase B: local = wires 4..7 ; lane = wires 0,1,2,3,8,9 ; wave = 10,11
//   Phase C: local = wires 8..11; lane = wires 0..5       ; wave = 6,7
// Boundary CNOTs: (3->4) per-lane select in B; (7->8) wave select in C;
// (11->0) folded into the C->A remap read / final measurement sign.
// ---------------------------------------------------------------------------

__global__ void qnn_prep(const float* __restrict__ w, float* __restrict__ coef) {
    const int g = threadIdx.x;
    if (g < NLAYERS * 12) {
        const float phi = w[g*3+0], th = w[g*3+1], om = w[g*3+2];
        const float ct = cosf(0.5f*th), st = sinf(0.5f*th);
        const float sp = 0.5f*(phi+om), dm = 0.5f*(phi-om);
        const float csp = cosf(sp), ssp = sinf(sp);
        const float cdm = cosf(dm), sdm = sinf(dm);
        float* c = coef + g*8;
        c[0] =  csp*ct; c[1] = -ssp*ct;   // a = e^{-i(phi+om)/2} ct
        c[2] = -cdm*st; c[3] = -sdm*st;   // b = -e^{+i(phi-om)/2} st
        c[4] =  cdm*st; c[5] = -sdm*st;   // c = e^{-i(phi-om)/2} st
        c[6] =  csp*ct; c[7] =  ssp*ct;   // d = e^{+i(phi+om)/2} ct
    }
}

__device__ __forceinline__ v2f cfma(float s, v2f a, v2f c) {
    v2f sv = {s, s};
    return __builtin_elementwise_fma(sv, a, c);
}

template<int BP>
__device__ __forceinline__ void rot_local(v2f (&v)[16], const float* __restrict__ cf) {
    const float ar = cf[0], ai = cf[1], br = cf[2], bi = cf[3];
    const float cr = cf[4], ci = cf[5], dr = cf[6], di = cf[7];
    #pragma unroll
    for (int l0 = 0; l0 < 16; ++l0) {
        if (!(l0 & (1 << BP))) {
            const int l1 = l0 | (1 << BP);
            const v2f u0 = v[l0], u1 = v[l1];
            const v2f t0 = {-u0.y, u0.x};    // i*u0
            const v2f t1 = {-u1.y, u1.x};    // i*u1
            const v2f sar = {ar, ar}, scr = {cr, cr};
            // v0' = a*u0 + b*u1 ; v1' = c*u0 + d*u1  (complex, packed)
            v[l0] = cfma(bi, t1, cfma(br, u1, cfma(ai, t0, sar * u0)));
            v[l1] = cfma(di, t1, cfma(dr, u1, cfma(ci, t0, scr * u0)));
        }
    }
}

#define SWAP_AMP(A,B) { v2f t_ = v[A]; v[A] = v[B]; v[B] = t_; }
// free ring-CNOTs inside a phase (ctrl bit3->tgt bit2, bit2->1, bit1->0):
#define RING_CNOTS_LOCAL() \
    SWAP_AMP(8,12) SWAP_AMP(9,13) SWAP_AMP(10,14) SWAP_AMP(11,15) \
    SWAP_AMP(4,6)  SWAP_AMP(5,7)  SWAP_AMP(12,14) SWAP_AMP(13,15) \
    SWAP_AMP(2,3)  SWAP_AMP(6,7)  SWAP_AMP(10,11) SWAP_AMP(14,15)

__global__ __launch_bounds__(256, 2) void qnn_kernel(
    const float* __restrict__ x,      // (512, 150528): only first 12 per row
    const float* __restrict__ coef,   // (72, 8) from qnn_prep
    const float* __restrict__ bias,   // scalar
    float* __restrict__ out)          // (512)
{
    __shared__ v2f st[2][4096];       // 64 KB double-buffered remap staging
    __shared__ float partial[4];

    const int tid  = threadIdx.x;     // 0..255
    const int lane = tid & 63;
    const int wv   = tid >> 6;        // 0..3
    const int b    = blockIdx.x;

    v2f v[16];
    int pb = 0;

    // ---- AngleEmbedding RX product state, built directly in phase A ----
    const float* xb = x + (size_t)b * XROW;
    float fc[12], fs[12];
    #pragma unroll
    for (int j = 0; j < 12; ++j) {
        const float h = xb[j] * 0.5f;
        fc[j] = __cosf(h);
        fs[j] = __sinf(h);
    }
    // fixed wires: 4..9 on lane bits 5..0, 10,11 on wave bits 1,0
    float pr = 1.f, pi_ = 0.f;
    #pragma unroll
    for (int j = 4; j < 12; ++j) {
        const int bit = (j < 10) ? ((lane >> (9 - j)) & 1)
                                 : ((j == 10) ? ((wv >> 1) & 1) : (wv & 1));
        const float nr = bit ? (pi_ * fs[j]) : (pr * fc[j]);
        const float ni = bit ? (-pr * fs[j]) : (pi_ * fc[j]);
        pr = nr; pi_ = ni;
    }
    // local wires 0..3 on local bits 3..0, doubling
    v[0] = (v2f){pr, pi_};
    #pragma unroll
    for (int bb = 0; bb < 4; ++bb) {
        const int wire = 3 - bb;          // bit bb hosts wire 3-bb
        const float cc = fc[wire], ss = fs[wire];
        const int m = 1 << bb;
        #pragma unroll
        for (int l = 0; l < 8; ++l) {
            if (l < m) {
                const float r = v[l].x, q = v[l].y;
                v[l + m] = (v2f){q * ss, -r * ss};
                v[l]     = (v2f){r * cc,  q * cc};
            }
        }
    }

    // ---- layers ----
    for (int layer = 0; layer < NLAYERS; ++layer) {
        const float* cl = coef + layer * 96;

        if (layer) {
            // remap C -> A, folding previous layer's CNOT(11->0)
            v2f* S = st[pb];
            #pragma unroll
            for (int l = 0; l < 16; ++l)
                S[(l << 8) | (tid ^ l ^ wv)] = v[l];
            __syncthreads();
            {
                const int l_old = ((lane & 3) << 2) | wv;
                const int w_old = (lane >> 2) & 3;
                const int n_lo  = (lane >> 4) & 3;
                const int fold  = (wv & 1) << 3;     // flip wire0 where wire11=1
                #pragma unroll
                for (int l = 0; l < 16; ++l) {
                    const int lp2   = l ^ fold;
                    const int n_old = (lp2 << 2) | n_lo;
                    const int t_old = (w_old << 6) | n_old;
                    v[l] = S[(l_old << 8) | (t_old ^ l_old ^ w_old)];
                }
            }
            pb ^= 1;   // next remap writes the other buffer; no 2nd barrier
        }

        // ---- phase A: Rot wires 0..3 (bp 3..0), CNOT(0->1),(1->2),(2->3) ----
        rot_local<3>(v, cl + 0*8);
        rot_local<2>(v, cl + 1*8);
        rot_local<1>(v, cl + 2*8);
        rot_local<0>(v, cl + 3*8);
        RING_CNOTS_LOCAL();

        // ---- remap A -> B ----
        {
            v2f* S = st[pb];
            #pragma unroll
            for (int l = 0; l < 16; ++l)
                S[(l << 8) | (tid ^ (l << 2))] = v[l];
            __syncthreads();
            const int l_old = (lane >> 2) & 0xF;
            const int n_lo  = lane & 3;
            #pragma unroll
            for (int l = 0; l < 16; ++l) {
                const int n_old = (l << 2) | n_lo;
                const int t_old = (wv << 6) | n_old;
                v[l] = S[(l_old << 8) | (t_old ^ (l_old << 2))];
            }
            pb ^= 1;
        }

        // ---- phase B: Rot wires 4..7, CNOT(3->4) cond, (4->5),(5->6),(6->7) ----
        rot_local<3>(v, cl + 4*8);
        rot_local<2>(v, cl + 5*8);
        rot_local<1>(v, cl + 6*8);
        rot_local<0>(v, cl + 7*8);
        {
            const bool sel = (lane >> 2) & 1;   // ctrl wire3 on lane bit N2
            #pragma unroll
            for (int l = 0; l < 8; ++l) {
                const v2f a0 = v[l], a1 = v[l + 8];
                v[l]     = sel ? a1 : a0;
                v[l + 8] = sel ? a0 : a1;
            }
        }
        RING_CNOTS_LOCAL();

        // ---- remap B -> C ----
        {
            v2f* S = st[pb];
            #pragma unroll
            for (int l = 0; l < 16; ++l) {
                const int sw = ((l & 1) << 3) | ((l & 2) << 1) | ((l & 4) >> 1) | ((l & 8) >> 3);
                S[(l << 8) | (tid ^ sw)] = v[l];
            }
            __syncthreads();
            const int l_old = ((lane & 3) << 2) | wv;
            const int swo = ((l_old & 1) << 3) | ((l_old & 2) << 1)
                          | ((l_old & 4) >> 1) | ((l_old & 8) >> 3);
            const int n_hi = ((lane >> 2) & 0xF) << 2;
            #pragma unroll
            for (int l = 0; l < 16; ++l) {
                const int n_old = n_hi | (l >> 2);
                const int w_old = l & 3;            // wires 10,11 from old wave
                const int t_old = (w_old << 6) | n_old;
                v[l] = S[(l_old << 8) | (t_old ^ swo)];
            }
            pb ^= 1;
        }

        // ---- phase C: Rot wires 8..11, CNOT(7->8) cond, (8->9),(9->10),(10->11) ----
        rot_local<3>(v, cl + 8*8);
        rot_local<2>(v, cl + 9*8);
        rot_local<1>(v, cl + 10*8);
        rot_local<0>(v, cl + 11*8);
        {
            const bool sel = wv & 1;            // ctrl wire7 on wave bit W0
            #pragma unroll
            for (int l = 0; l < 8; ++l) {
                const v2f a0 = v[l], a1 = v[l + 8];
                v[l]     = sel ? a1 : a0;
                v[l + 8] = sel ? a0 : a1;
            }
        }
        RING_CNOTS_LOCAL();
        // CNOT(11->0) folded into next remap / final measurement sign
    }

    // ---- <Z_0> with folded CNOT(11->0): sign = wire0 ^ wire11 = lane[5] ^ l[0]
    float acc = 0.f;
    #pragma unroll
    for (int l = 0; l < 16; ++l) {
        const float p = v[l].x * v[l].x + v[l].y * v[l].y;
        acc += ((((lane >> 5) ^ l) & 1) ? -p : p);
    }
    #pragma unroll
    for (int off = 32; off > 0; off >>= 1)
        acc += __shfl_down(acc, off, 64);
    if (lane == 0) partial[wv] = acc;
    __syncthreads();
    if (tid == 0)
        out[b] = partial[0] + partial[1] + partial[2] + partial[3] + bias[0];
}

extern "C" void kernel_launch(void* const* d_in, const int* in_sizes, int n_in,
                              void* d_out, int out_size, void* d_ws, size_t ws_size,
                              hipStream_t stream) {
    const float* x    = (const float*)d_in[0];
    const float* wts  = (const float*)d_in[1];
    const float* bias = (const float*)d_in[2];
    float* out  = (float*)d_out;
    float* coef = (float*)d_ws;       // 72*8 floats = 2304 B
    qnn_prep<<<1, 128, 0, stream>>>(wts, coef);
    qnn_kernel<<<out_size, 256, 0, stream>>>(x, coef, bias, out);
}

// Round 5
// 370.323 us; speedup vs baseline: 1.5616x; 1.0026x over previous
//
#include <hip/hip_runtime.h>

#define NLAYERS 6
#define XROW 150528   // 3*224*224

typedef float v2f __attribute__((ext_vector_type(2)));

// ---------------------------------------------------------------------------
// 12-qubit state-vector sim, one block (8 waves, 512 threads) per batch elem.
// 8 amplitudes per lane (3 local bits L2..L0), 6 lane bits, 3 wave bits.
// Four phases, each hosting 3 consecutive wires locally; the phase mappings
// are a bit-rotation group so ONE remap permutation serves all transitions:
//   new l = old_lane>>3 ; new lane = ((old_lane&7)<<3)|old_wv ; new wv = old l
// Phase p: local L2,L1,L0 = wires 3p,3p+1,3p+2.
//   P0: lane N5..N0 = wires 3..8,  wv = wires 9,10,11
//   P1: lane = wires 6..11, wv = wires 0,1,2   (ctrl wire2 = W0)
//   P2: lane = wires 9,10,11,0,1,2, wv = 3,4,5 (ctrl wire5 = W0)
//   P3: lane = wires 0..5, wv = 6,7,8          (ctrl wire8 = W0)
// Ring CNOTs: 2 per phase free (local renames); boundary CNOT (3p-1 -> 3p)
// is a wave-uniform select (ctrl always W0); CNOT(11->0) folds into the
// P3->P0 remap (l ^= (wv&1)<<2) or the final measurement sign.
// LDS slot: (l<<9)|(lane<<3)|(wv ^ ((lane>>1)&7)) -> 4-way (b64 floor) on
// both write and read sides. Double-buffered: ONE barrier per remap.
// ---------------------------------------------------------------------------

__global__ void qnn_prep(const float* __restrict__ w, float* __restrict__ coef) {
    const int g = threadIdx.x;
    if (g < NLAYERS * 12) {
        const float phi = w[g*3+0], th = w[g*3+1], om = w[g*3+2];
        const float ct = cosf(0.5f*th), st = sinf(0.5f*th);
        const float sp = 0.5f*(phi+om), dm = 0.5f*(phi-om);
        const float csp = cosf(sp), ssp = sinf(sp);
        const float cdm = cosf(dm), sdm = sinf(dm);
        float* c = coef + g*8;
        c[0] =  csp*ct; c[1] = -ssp*ct;   // a = e^{-i(phi+om)/2} ct
        c[2] = -cdm*st; c[3] = -sdm*st;   // b = -e^{+i(phi-om)/2} st
        c[4] =  cdm*st; c[5] = -sdm*st;   // c = e^{-i(phi-om)/2} st
        c[6] =  csp*ct; c[7] =  ssp*ct;   // d = e^{+i(phi+om)/2} ct
    }
}

__device__ __forceinline__ v2f cfma(float s, v2f a, v2f c) {
    v2f sv = {s, s};
    return __builtin_elementwise_fma(sv, a, c);
}

template<int BP>
__device__ __forceinline__ void rot_local(v2f (&v)[8], const float* __restrict__ cf) {
    const float ar = cf[0], ai = cf[1], br = cf[2], bi = cf[3];
    const float cr = cf[4], ci = cf[5], dr = cf[6], di = cf[7];
    #pragma unroll
    for (int l0 = 0; l0 < 8; ++l0) {
        if (!(l0 & (1 << BP))) {
            const int l1 = l0 | (1 << BP);
            const v2f u0 = v[l0], u1 = v[l1];
            const v2f t0 = {-u0.y, u0.x};    // i*u0
            const v2f t1 = {-u1.y, u1.x};    // i*u1
            const v2f sar = {ar, ar}, scr = {cr, cr};
            v[l0] = cfma(bi, t1, cfma(br, u1, cfma(ai, t0, sar * u0)));
            v[l1] = cfma(di, t1, cfma(dr, u1, cfma(ci, t0, scr * u0)));
        }
    }
}

#define SWAP_AMP(A,B) { v2f t_ = v[A]; v[A] = v[B]; v[B] = t_; }
// CN(L2->L1): swap 4<->6, 5<->7 ; CN(L1->L0): swap 2<->3, 6<->7
#define RING_CNOTS_LOCAL() \
    SWAP_AMP(4,6) SWAP_AMP(5,7) SWAP_AMP(2,3) SWAP_AMP(6,7)

__global__ __launch_bounds__(512, 4) void qnn_kernel(
    const float* __restrict__ x,      // (512, 150528): only first 12 per row
    const float* __restrict__ coef,   // (72, 8) from qnn_prep
    const float* __restrict__ bias,   // scalar
    float* __restrict__ out)          // (512)
{
    __shared__ v2f st[2][4096];       // 64 KB double-buffered remap staging
    __shared__ float partial[8];

    const int tid  = threadIdx.x;     // 0..511
    const int lane = tid & 63;
    const int wv   = tid >> 6;        // 0..7
    const int b    = blockIdx.x;

    v2f v[8];
    int pb = 0;

    // hoisted remap address pieces
    const int wbase = (lane << 3) | (wv ^ ((lane >> 1) & 7));  // write: | (l<<9)
    const int rbase = wv << 9;                                  // old_l = new wv
    const int u     = lane >> 3;
    const int w7    = lane & 7;

    // ---- AngleEmbedding RX product state, built directly in P0 mapping ----
    const float* xb = x + (size_t)b * XROW;
    float fc[12], fs[12];
    #pragma unroll
    for (int j = 0; j < 12; ++j) {
        const float h = xb[j] * 0.5f;
        fc[j] = __cosf(h);
        fs[j] = __sinf(h);
    }
    // wires 3..8 on lane bits 5..0; wires 9,10,11 on wv bits 2,1,0
    float pr = 1.f, pi_ = 0.f;
    #pragma unroll
    for (int j = 3; j < 12; ++j) {
        const int bit = (j < 9) ? ((lane >> (8 - j)) & 1)
                                : ((wv >> (11 - j)) & 1);
        const float nr = bit ? (pi_ * fs[j]) : (pr * fc[j]);
        const float ni = bit ? (-pr * fs[j]) : (pi_ * fc[j]);
        pr = nr; pi_ = ni;
    }
    // wires 0,1,2 on local bits 2,1,0 (wire j on bit 2-j), doubling
    v[0] = (v2f){pr, pi_};
    #pragma unroll
    for (int bb = 0; bb < 3; ++bb) {
        const int wire = 2 - bb;
        const float cc = fc[wire], ss = fs[wire];
        const int m = 1 << bb;
        #pragma unroll
        for (int l = 0; l < 4; ++l) {
            if (l < m) {
                const float r = v[l].x, q = v[l].y;
                v[l + m] = (v2f){q * ss, -r * ss};
                v[l]     = (v2f){r * cc,  q * cc};
            }
        }
    }

    // ---- layers ----
    for (int layer = 0; layer < NLAYERS; ++layer) {
        const float* cl = coef + layer * 96;

        #pragma unroll
        for (int p = 0; p < 4; ++p) {
            // remap into phase p (skip for very first phase of layer 0)
            if (layer || p) {
                const int fold = (p == 0) ? ((wv & 1) << 2) : 0;  // CN(11->0)
                v2f* S = st[pb];
                #pragma unroll
                for (int l = 0; l < 8; ++l)
                    S[(l << 9) | wbase] = v[l];
                __syncthreads();
                #pragma unroll
                for (int l = 0; l < 8; ++l) {
                    const int ol = ((l ^ fold) << 3) | u;          // old_lane
                    v[l] = S[rbase | (ol << 3) | (w7 ^ ((ol >> 1) & 7))];
                }
                pb ^= 1;
            }

            // Rot gates: wire 3p on L2, 3p+1 on L1, 3p+2 on L0
            rot_local<2>(v, cl + (3 * p + 0) * 8);
            rot_local<1>(v, cl + (3 * p + 1) * 8);
            rot_local<0>(v, cl + (3 * p + 2) * 8);

            // boundary CNOT (3p-1 -> 3p): ctrl = W0, tgt = L2  (phases 1..3)
            if (p) {
                const bool sel = wv & 1;
                #pragma unroll
                for (int l = 0; l < 4; ++l) {
                    const v2f a0 = v[l], a1 = v[l + 4];
                    v[l]     = sel ? a1 : a0;
                    v[l + 4] = sel ? a0 : a1;
                }
            }
            // local ring CNOTs (3p->3p+1), (3p+1->3p+2)
            RING_CNOTS_LOCAL();
        }
        // CN(11->0) folded into next P3->P0 remap / final measurement sign
    }

    // ---- <Z_0> with folded CNOT(11->0): sign = b11 ^ b0 = lane[5] ^ l[0] ----
    float acc = 0.f;
    #pragma unroll
    for (int l = 0; l < 8; ++l) {
        const float p = v[l].x * v[l].x + v[l].y * v[l].y;
        acc += ((((lane >> 5) ^ l) & 1) ? -p : p);
    }
    #pragma unroll
    for (int off = 32; off > 0; off >>= 1)
        acc += __shfl_down(acc, off, 64);
    if (lane == 0) partial[wv] = acc;
    __syncthreads();
    if (tid == 0) {
        float s = 0.f;
        #pragma unroll
        for (int i = 0; i < 8; ++i) s += partial[i];
        out[b] = s + bias[0];
    }
}

extern "C" void kernel_launch(void* const* d_in, const int* in_sizes, int n_in,
                              void* d_out, int out_size, void* d_ws, size_t ws_size,
                              hipStream_t stream) {
    const float* x    = (const float*)d_in[0];
    const float* wts  = (const float*)d_in[1];
    const float* bias = (const float*)d_in[2];
    float* out  = (float*)d_out;
    float* coef = (float*)d_ws;       // 72*8 floats = 2304 B
    qnn_prep<<<1, 128, 0, stream>>>(wts, coef);
    qnn_kernel<<<out_size, 512, 0, stream>>>(x, coef, bias, out);
}